// Round 8
// baseline (1853.654 us; speedup 1.0000x reference)
//
#include <hip/hip_runtime.h>

// Problem constants (static from reference setup_inputs)
constexpr int BB = 8, CC = 4, HH = 1024, WW = 1024, CROP = 5;
constexpr int HC = HH - 2 * CROP, WC = WW - 2 * CROP;   // 1014 x 1014
constexpr int HW = HH * WW;
constexpr float AA = -0.75f;                            // PyTorch bicubic A

constexpr int PBLK = 1536;                  // persistent blocks (6/CU)
constexpr int NSEG = BB * HC * 4;           // segments: (b, y, chunk-of-256)

typedef float f4 __attribute__((ext_vector_type(4)));
typedef f4 uf4 __attribute__((aligned(4)));  // dword-aligned vec4 load

// reflection valid for |i| <= 2046
__device__ __forceinline__ int reflect_small(int i) {
    int r = i < 0 ? -i : i;
    return r > (HH - 1) ? 2 * (HH - 1) - r : r;
}

__device__ __forceinline__ void cubic_w(float t, float& w0, float& w1,
                                        float& w2, float& w3) {
    float t1 = t + 1.0f;
    w0 = ((AA * t1 - 5.0f * AA) * t1 + 8.0f * AA) * t1 - 4.0f * AA;
    w1 = ((AA + 2.0f) * t - (AA + 3.0f)) * t * t + 1.0f;
    float s = 1.0f - t;
    w2 = ((AA + 2.0f) * s - (AA + 3.0f)) * s * s + 1.0f;
    float s2 = 2.0f - t;
    w3 = ((AA * s2 - 5.0f * AA) * s2 + 8.0f * AA) * s2 - 4.0f * AA;
}

// rare fallback (~0.3% of pixels): scalar reflected global taps, all channels
__device__ __noinline__ float px_slow(const float* __restrict__ tgt_b,
                                      const float* __restrict__ in_b, int pix,
                                      int bx, int by, float wx0, float wx1,
                                      float wx2, float wx3, float wy0,
                                      float wy1, float wy2, float wy3) {
    const int r0 = reflect_small(by - 1) * WW;
    const int r1 = reflect_small(by) * WW;
    const int r2 = reflect_small(by + 1) * WW;
    const int r3 = reflect_small(by + 2) * WW;
    const int c0 = reflect_small(bx - 1);
    const int c1 = reflect_small(bx);
    const int c2 = reflect_small(bx + 1);
    const int c3 = reflect_small(bx + 2);
    float acc = 0.0f;
#pragma unroll
    for (int c = 0; c < CC; ++c) {
        const float* tb = tgt_b + c * HW;
        float q0 = wx0 * tb[r0 + c0] + wx1 * tb[r0 + c1] + wx2 * tb[r0 + c2] +
                   wx3 * tb[r0 + c3];
        float q1 = wx0 * tb[r1 + c0] + wx1 * tb[r1 + c1] + wx2 * tb[r1 + c2] +
                   wx3 * tb[r1 + c3];
        float q2 = wx0 * tb[r2 + c0] + wx1 * tb[r2 + c1] + wx2 * tb[r2 + c2] +
                   wx3 * tb[r2 + c3];
        float q3 = wx0 * tb[r3 + c0] + wx1 * tb[r3 + c1] + wx2 * tb[r3 + c2] +
                   wx3 * tb[r3 + c3];
        float v = wy0 * q0 + wy1 * q1 + wy2 * q2 + wy3 * q3;
        acc += fabsf(in_b[c * HW + pix] - v);
    }
    return acc;
}

__global__ __launch_bounds__(256, 6) void warp_loss_k(
    const float* __restrict__ input, const float* __restrict__ target,
    const float* __restrict__ flow, float* __restrict__ wsbuf) {
    const int tid = (int)threadIdx.x;
    const int wv = tid >> 6, lane = tid & 63;
    float lsum = 0.0f;

    for (int seg = blockIdx.x; seg < NSEG; seg += PBLK) {
        const int chunk = seg & 3;
        const int row = seg >> 2;
        const int y = row % HC + CROP;
        const int b = row / HC;
        const int x = CROP + chunk * 256 + tid;
        const bool valid = x <= 1018;
        const int xc = valid ? x : 1018;      // clamp tail lanes (discarded)

        const float* tgt_b = target + (size_t)b * CC * HW;
        const float* in_b = input + (size_t)b * CC * HW;
        const float* flow_b = flow + (size_t)b * 2 * HW;
        const int pix = y * WW + xc;

        // coalesced per-pixel loads (issued together)
        const float dx = flow_b[pix];
        const float dy = flow_b[HW + pix];
        const float i0v = in_b[pix];
        const float i1v = in_b[HW + pix];
        const float i2v = in_b[2 * HW + pix];
        const float i3v = in_b[3 * HW + pix];

        const float fx = (float)xc + dx;
        const float fy = (float)y + dy;
        const float bxf = floorf(fx), byf = floorf(fy);
        const int bx = (int)bxf, by = (int)byf;
        const float tx = fx - bxf, ty = fy - byf;

        float wx0, wx1, wx2, wx3, wy0, wy1, wy2, wy3;
        cubic_w(tx, wx0, wx1, wx2, wx3);
        cubic_w(ty, wy0, wy1, wy2, wy3);

        // fast path: tap rows within [y-4, y+4] and cols contiguous in-bounds
        const int d = by - y;                  // fast iff d in [-3, 2]
        const bool fastr = (d >= -3) & (d <= 2);
        const bool fastc = (bx >= 1) & (bx <= WW - 3);
        const bool fast = valid && fastr && fastc;
        const bool slow = valid && !fast;

        // safe per-lane column offset (slow lanes read dummy, discarded)
        const int off = (fastc ? bx : 512) - 1;

        // row-decomposed gather: 9 rows r = y-4 .. y+4, all lanes same row.
        // weight w = wy[j], j = (r - by + 1) = i - 3 - d; 0 outside [0,3].
        const float* rowp = tgt_b + (size_t)(y - 4) * WW + off;
        float v0 = 0.0f, v1 = 0.0f, v2 = 0.0f, v3 = 0.0f;
#pragma unroll
        for (int i = 0; i < 9; ++i) {
            f4 a0 = *(const uf4*)(rowp);
            f4 a1 = *(const uf4*)(rowp + HW);
            f4 a2 = *(const uf4*)(rowp + 2 * HW);
            f4 a3 = *(const uf4*)(rowp + 3 * HW);
            const int j = i - 3 - d;
            const float w = (j == 0) ? wy0 : (j == 1) ? wy1
                            : (j == 2) ? wy2 : (j == 3) ? wy3 : 0.0f;
            float q0 = a0.x * wx0 + a0.y * wx1 + a0.z * wx2 + a0.w * wx3;
            float q1 = a1.x * wx0 + a1.y * wx1 + a1.z * wx2 + a1.w * wx3;
            float q2 = a2.x * wx0 + a2.y * wx1 + a2.z * wx2 + a2.w * wx3;
            float q3 = a3.x * wx0 + a3.y * wx1 + a3.z * wx2 + a3.w * wx3;
            v0 += w * q0;
            v1 += w * q1;
            v2 += w * q2;
            v3 += w * q3;
            rowp += WW;
        }

        if (fast) {
            lsum += fabsf(i0v - v0) + fabsf(i1v - v1) + fabsf(i2v - v2) +
                    fabsf(i3v - v3);
        }
        if (slow) {
            lsum += px_slow(tgt_b, in_b, pix, bx, by, wx0, wx1, wx2, wx3,
                            wy0, wy1, wy2, wy3);
        }
    }

    // wave-64 shuffle reduction + per-block partial (no global atomic)
#pragma unroll
    for (int off2 = 32; off2 > 0; off2 >>= 1) lsum += __shfl_down(lsum, off2);

    __shared__ float sm[4];
    if (lane == 0) sm[wv] = lsum;
    __syncthreads();
    if (tid == 0) wsbuf[blockIdx.x] = sm[0] + sm[1] + sm[2] + sm[3];
}

__global__ __launch_bounds__(1024) void reduce_k(const float* __restrict__ ws,
                                                 float* __restrict__ out) {
    float s = 0.0f;
    for (int i = threadIdx.x; i < PBLK; i += 1024) s += ws[i];
#pragma unroll
    for (int off = 32; off > 0; off >>= 1) s += __shfl_down(s, off);
    __shared__ float sm[16];
    const int lane = threadIdx.x & 63;
    const int wv = threadIdx.x >> 6;
    if (lane == 0) sm[wv] = s;
    __syncthreads();
    if (threadIdx.x == 0) {
        float t = 0.0f;
#pragma unroll
        for (int i = 0; i < 16; ++i) t += sm[i];
        constexpr float inv_count = 1.0f / ((float)BB * CC * HC * WC);
        out[0] = t * inv_count;
    }
}

extern "C" void kernel_launch(void* const* d_in, const int* in_sizes, int n_in,
                              void* d_out, int out_size, void* d_ws,
                              size_t ws_size, hipStream_t stream) {
    const float* input = (const float*)d_in[0];
    const float* target = (const float*)d_in[1];
    const float* flow = (const float*)d_in[2];
    float* ws = (float*)d_ws;
    float* out = (float*)d_out;

    warp_loss_k<<<PBLK, 256, 0, stream>>>(input, target, flow, ws);
    reduce_k<<<1, 1024, 0, stream>>>(ws, out);
}

// Round 9
// 186.542 us; speedup vs baseline: 9.9369x; 9.9369x over previous
//
#include <hip/hip_runtime.h>

// Problem constants (static from reference setup_inputs)
constexpr int BB = 8, CC = 4, HH = 1024, WW = 1024, CROP = 5;
constexpr int HC = HH - 2 * CROP, WC = WW - 2 * CROP;   // 1014 x 1014
constexpr int HW = HH * WW;
constexpr float AA = -0.75f;                            // PyTorch bicubic A

constexpr int PBLK = 1024;                  // persistent blocks (4/CU at LB(256,4))
constexpr int NSEG = BB * HC * 4;           // segments: (b, y, chunk-of-256)

typedef float f4 __attribute__((ext_vector_type(4)));
typedef f4 uf4 __attribute__((aligned(4)));  // dword-aligned vec4 load

// reflection valid for |i| <= 2046
__device__ __forceinline__ int reflect_small(int i) {
    int r = i < 0 ? -i : i;
    return r > (HH - 1) ? 2 * (HH - 1) - r : r;
}

__device__ __forceinline__ void cubic_w(float t, float& w0, float& w1,
                                        float& w2, float& w3) {
    float t1 = t + 1.0f;
    w0 = ((AA * t1 - 5.0f * AA) * t1 + 8.0f * AA) * t1 - 4.0f * AA;
    w1 = ((AA + 2.0f) * t - (AA + 3.0f)) * t * t + 1.0f;
    float s = 1.0f - t;
    w2 = ((AA + 2.0f) * s - (AA + 3.0f)) * s * s + 1.0f;
    float s2 = 2.0f - t;
    w3 = ((AA * s2 - 5.0f * AA) * s2 + 8.0f * AA) * s2 - 4.0f * AA;
}

// rare fallback (~0.3% of pixels): scalar reflected global taps, all channels
__device__ __noinline__ float px_slow(const float* __restrict__ tgt_b,
                                      const float* __restrict__ in_b, int pix,
                                      int bx, int by, float wx0, float wx1,
                                      float wx2, float wx3, float wy0,
                                      float wy1, float wy2, float wy3) {
    const int r0 = reflect_small(by - 1) * WW;
    const int r1 = reflect_small(by) * WW;
    const int r2 = reflect_small(by + 1) * WW;
    const int r3 = reflect_small(by + 2) * WW;
    const int c0 = reflect_small(bx - 1);
    const int c1 = reflect_small(bx);
    const int c2 = reflect_small(bx + 1);
    const int c3 = reflect_small(bx + 2);
    float acc = 0.0f;
#pragma unroll
    for (int c = 0; c < CC; ++c) {
        const float* tb = tgt_b + c * HW;
        float q0 = wx0 * tb[r0 + c0] + wx1 * tb[r0 + c1] + wx2 * tb[r0 + c2] +
                   wx3 * tb[r0 + c3];
        float q1 = wx0 * tb[r1 + c0] + wx1 * tb[r1 + c1] + wx2 * tb[r1 + c2] +
                   wx3 * tb[r1 + c3];
        float q2 = wx0 * tb[r2 + c0] + wx1 * tb[r2 + c1] + wx2 * tb[r2 + c2] +
                   wx3 * tb[r2 + c3];
        float q3 = wx0 * tb[r3 + c0] + wx1 * tb[r3 + c1] + wx2 * tb[r3 + c2] +
                   wx3 * tb[r3 + c3];
        float v = wy0 * q0 + wy1 * q1 + wy2 * q2 + wy3 * q3;
        acc += fabsf(in_b[c * HW + pix] - v);
    }
    return acc;
}

__device__ __forceinline__ float dot4(const f4& a, float w0, float w1,
                                      float w2, float w3) {
    return a.x * w0 + a.y * w1 + a.z * w2 + a.w * w3;
}

__global__ __launch_bounds__(256, 4) void warp_loss_k(
    const float* __restrict__ input, const float* __restrict__ target,
    const float* __restrict__ flow, float* __restrict__ wsbuf) {
    const int tid = (int)threadIdx.x;
    const int wv = tid >> 6, lane = tid & 63;
    float lsum = 0.0f;

    for (int seg = blockIdx.x; seg < NSEG; seg += PBLK) {
        const int chunk = seg & 3;
        const int row = seg >> 2;
        const int y = row % HC + CROP;
        const int b = row / HC;
        const int x = CROP + chunk * 256 + tid;
        if (x > 1018) continue;  // only chunk-3 tail lanes

        const float* tgt_b = target + (size_t)b * CC * HW;
        const float* in_b = input + (size_t)b * CC * HW;
        const float* flow_b = flow + (size_t)b * 2 * HW;
        const int pix = y * WW + x;

        const float dx = flow_b[pix];
        const float dy = flow_b[HW + pix];

        const float fx = (float)x + dx;
        const float fy = (float)y + dy;
        const float bxf = floorf(fx), byf = floorf(fy);
        const int bx = (int)bxf, by = (int)byf;
        const float tx = fx - bxf, ty = fy - byf;

        float wx0, wx1, wx2, wx3, wy0, wy1, wy2, wy3;
        cubic_w(tx, wx0, wx1, wx2, wx3);
        cubic_w(ty, wy0, wy1, wy2, wy3);

        const int r0 = reflect_small(by - 1) * WW;
        const int r1 = reflect_small(by) * WW;
        const int r2 = reflect_small(by + 1) * WW;
        const int r3 = reflect_small(by + 2) * WW;

        const bool fastc = (bx >= 1) & (bx <= WW - 3);
        // slow lanes gather from a harmless dummy column (discarded)
        const float* tbase = tgt_b + ((fastc ? bx : 512) - 1);

        // ---- issue ALL 20 loads; sched_barrier(0) forbids sinking them ----
        f4 A00 = *(const uf4*)(tbase + r0);
        f4 A01 = *(const uf4*)(tbase + r1);
        f4 A02 = *(const uf4*)(tbase + r2);
        f4 A03 = *(const uf4*)(tbase + r3);
        f4 A10 = *(const uf4*)(tbase + HW + r0);
        f4 A11 = *(const uf4*)(tbase + HW + r1);
        f4 A12 = *(const uf4*)(tbase + HW + r2);
        f4 A13 = *(const uf4*)(tbase + HW + r3);
        f4 A20 = *(const uf4*)(tbase + 2 * HW + r0);
        f4 A21 = *(const uf4*)(tbase + 2 * HW + r1);
        f4 A22 = *(const uf4*)(tbase + 2 * HW + r2);
        f4 A23 = *(const uf4*)(tbase + 2 * HW + r3);
        f4 A30 = *(const uf4*)(tbase + 3 * HW + r0);
        f4 A31 = *(const uf4*)(tbase + 3 * HW + r1);
        f4 A32 = *(const uf4*)(tbase + 3 * HW + r2);
        f4 A33 = *(const uf4*)(tbase + 3 * HW + r3);
        const float i0v = in_b[pix];
        const float i1v = in_b[HW + pix];
        const float i2v = in_b[2 * HW + pix];
        const float i3v = in_b[3 * HW + pix];
        __builtin_amdgcn_sched_barrier(0);
        // ---- consume ----

        if (fastc) {
            float v0 = wy0 * dot4(A00, wx0, wx1, wx2, wx3) +
                       wy1 * dot4(A01, wx0, wx1, wx2, wx3) +
                       wy2 * dot4(A02, wx0, wx1, wx2, wx3) +
                       wy3 * dot4(A03, wx0, wx1, wx2, wx3);
            float v1 = wy0 * dot4(A10, wx0, wx1, wx2, wx3) +
                       wy1 * dot4(A11, wx0, wx1, wx2, wx3) +
                       wy2 * dot4(A12, wx0, wx1, wx2, wx3) +
                       wy3 * dot4(A13, wx0, wx1, wx2, wx3);
            float v2 = wy0 * dot4(A20, wx0, wx1, wx2, wx3) +
                       wy1 * dot4(A21, wx0, wx1, wx2, wx3) +
                       wy2 * dot4(A22, wx0, wx1, wx2, wx3) +
                       wy3 * dot4(A23, wx0, wx1, wx2, wx3);
            float v3 = wy0 * dot4(A30, wx0, wx1, wx2, wx3) +
                       wy1 * dot4(A31, wx0, wx1, wx2, wx3) +
                       wy2 * dot4(A32, wx0, wx1, wx2, wx3) +
                       wy3 * dot4(A33, wx0, wx1, wx2, wx3);
            lsum += fabsf(i0v - v0) + fabsf(i1v - v1) + fabsf(i2v - v2) +
                    fabsf(i3v - v3);
        } else {
            lsum += px_slow(tgt_b, in_b, pix, bx, by, wx0, wx1, wx2, wx3,
                            wy0, wy1, wy2, wy3);
        }
    }

    // wave-64 shuffle reduction + per-block partial (no global atomic)
#pragma unroll
    for (int off2 = 32; off2 > 0; off2 >>= 1) lsum += __shfl_down(lsum, off2);

    __shared__ float sm[4];
    if (lane == 0) sm[wv] = lsum;
    __syncthreads();
    if (tid == 0) wsbuf[blockIdx.x] = sm[0] + sm[1] + sm[2] + sm[3];
}

__global__ __launch_bounds__(1024) void reduce_k(const float* __restrict__ ws,
                                                 float* __restrict__ out) {
    float s = 0.0f;
    for (int i = threadIdx.x; i < PBLK; i += 1024) s += ws[i];
#pragma unroll
    for (int off = 32; off > 0; off >>= 1) s += __shfl_down(s, off);
    __shared__ float sm[16];
    const int lane = threadIdx.x & 63;
    const int wv = threadIdx.x >> 6;
    if (lane == 0) sm[wv] = s;
    __syncthreads();
    if (threadIdx.x == 0) {
        float t = 0.0f;
#pragma unroll
        for (int i = 0; i < 16; ++i) t += sm[i];
        constexpr float inv_count = 1.0f / ((float)BB * CC * HC * WC);
        out[0] = t * inv_count;
    }
}

extern "C" void kernel_launch(void* const* d_in, const int* in_sizes, int n_in,
                              void* d_out, int out_size, void* d_ws,
                              size_t ws_size, hipStream_t stream) {
    const float* input = (const float*)d_in[0];
    const float* target = (const float*)d_in[1];
    const float* flow = (const float*)d_in[2];
    float* ws = (float*)d_ws;
    float* out = (float*)d_out;

    warp_loss_k<<<PBLK, 256, 0, stream>>>(input, target, flow, ws);
    reduce_k<<<1, 1024, 0, stream>>>(ws, out);
}

// Round 11
// 172.135 us; speedup vs baseline: 10.7686x; 1.0837x over previous
//
#include <hip/hip_runtime.h>

// Problem constants (static from reference setup_inputs)
constexpr int BB = 8, CC = 4, HH = 1024, WW = 1024, CROP = 5;
constexpr int HC = HH - 2 * CROP, WC = WW - 2 * CROP;   // 1014 x 1014
constexpr int HW = HH * WW;
constexpr float AA = -0.75f;                            // PyTorch bicubic A

constexpr int PBLK = 1024;                  // 4 blocks/CU at __launch_bounds__(256,4)
constexpr int NSEG = BB * HC * 4;           // segments: (b, y, chunk-of-256)

typedef float f4 __attribute__((ext_vector_type(4)));

// reflection valid for |i| <= 2046
__device__ __forceinline__ int reflect_small(int i) {
    int r = i < 0 ? -i : i;
    return r > (HH - 1) ? 2 * (HH - 1) - r : r;
}

__device__ __forceinline__ void cubic_w(float t, float& w0, float& w1,
                                        float& w2, float& w3) {
    float t1 = t + 1.0f;
    w0 = ((AA * t1 - 5.0f * AA) * t1 + 8.0f * AA) * t1 - 4.0f * AA;
    w1 = ((AA + 2.0f) * t - (AA + 3.0f)) * t * t + 1.0f;
    float s = 1.0f - t;
    w2 = ((AA + 2.0f) * s - (AA + 3.0f)) * s * s + 1.0f;
    float s2 = 2.0f - t;
    w3 = ((AA * s2 - 5.0f * AA) * s2 + 8.0f * AA) * s2 - 4.0f * AA;
}

// rare fallback (~0.4% of pixels, x-edge columns): scalar reflected taps
__device__ __noinline__ float px_slow(const float* __restrict__ tgt_b,
                                      const float* __restrict__ in_b, int pix,
                                      int bx, int by, float wx0, float wx1,
                                      float wx2, float wx3, float wy0,
                                      float wy1, float wy2, float wy3) {
    const int r0 = reflect_small(by - 1) * WW;
    const int r1 = reflect_small(by) * WW;
    const int r2 = reflect_small(by + 1) * WW;
    const int r3 = reflect_small(by + 2) * WW;
    const int c0 = reflect_small(bx - 1);
    const int c1 = reflect_small(bx);
    const int c2 = reflect_small(bx + 1);
    const int c3 = reflect_small(bx + 2);
    float acc = 0.0f;
#pragma unroll
    for (int c = 0; c < CC; ++c) {
        const float* tb = tgt_b + c * HW;
        float q0 = wx0 * tb[r0 + c0] + wx1 * tb[r0 + c1] + wx2 * tb[r0 + c2] +
                   wx3 * tb[r0 + c3];
        float q1 = wx0 * tb[r1 + c0] + wx1 * tb[r1 + c1] + wx2 * tb[r1 + c2] +
                   wx3 * tb[r1 + c3];
        float q2 = wx0 * tb[r2 + c0] + wx1 * tb[r2 + c1] + wx2 * tb[r2 + c2] +
                   wx3 * tb[r2 + c3];
        float q3 = wx0 * tb[r3 + c0] + wx1 * tb[r3 + c1] + wx2 * tb[r3 + c2] +
                   wx3 * tb[r3 + c3];
        float v = wy0 * q0 + wy1 * q1 + wy2 * q2 + wy3 * q3;
        acc += fabsf(in_b[c * HW + pix] - v);
    }
    return acc;
}

__device__ __forceinline__ float dot4(const f4& a, float w0, float w1,
                                      float w2, float w3) {
    return a.x * w0 + a.y * w1 + a.z * w2 + a.w * w3;
}

__global__ __launch_bounds__(256, 4) void warp_loss_k(
    const float* __restrict__ input, const float* __restrict__ target,
    const float* __restrict__ flow, float* __restrict__ wsbuf) {
    const int tid = (int)threadIdx.x;
    const int wv = tid >> 6, lane = tid & 63;
    float lsum = 0.0f;

    int seg = blockIdx.x;
    float dxn = 0.0f, dyn = 0.0f;
    if (seg < NSEG) {  // prologue: flow for first segment (compiler-handled)
        const int chunk = seg & 3, row = seg >> 2;
        const int y = row % HC + CROP, b = row / HC;
        int x = CROP + chunk * 256 + tid;
        x = x > 1018 ? 1018 : x;
        const float* fb = flow + (size_t)b * 2 * HW;
        dxn = fb[y * WW + x];
        dyn = fb[HW + y * WW + x];
    }

    for (; seg < NSEG; seg += PBLK) {
        const float dx = dxn, dy = dyn;
        const int chunk = seg & 3, row = seg >> 2;
        const int y = row % HC + CROP, b = row / HC;
        const int xr = CROP + chunk * 256 + tid;
        const bool valid = xr <= 1018;
        const int x = valid ? xr : 1018;
        const int pix = y * WW + x;

        const float* tgt_b = target + (size_t)b * CC * HW;
        const float* in_b = input + (size_t)b * CC * HW;

        const float fx = (float)x + dx;
        const float fy = (float)y + dy;
        const float bxf = floorf(fx), byf = floorf(fy);
        const int bx = (int)bxf, by = (int)byf;
        const float tx = fx - bxf, ty = fy - byf;

        float wx0, wx1, wx2, wx3, wy0, wy1, wy2, wy3;
        cubic_w(tx, wx0, wx1, wx2, wx3);
        cubic_w(ty, wy0, wy1, wy2, wy3);

        // row byte-offsets (reflection exact for any |dy| we can see)
        const bool fastc = (bx >= 1) & (bx <= WW - 3);
        const unsigned cb = (unsigned)((fastc ? bx : 512) - 1) * 4u;
        const unsigned o0 = (unsigned)(reflect_small(by - 1) * WW) * 4u + cb;
        const unsigned o1 = (unsigned)(reflect_small(by) * WW) * 4u + cb;
        const unsigned o2 = (unsigned)(reflect_small(by + 1) * WW) * 4u + cb;
        const unsigned o3 = (unsigned)(reflect_small(by + 2) * WW) * 4u + cb;
        const unsigned po = (unsigned)pix * 4u;

        // next-iteration flow prefetch address (clamped on last iter)
        const int nseg = (seg + PBLK < NSEG) ? seg + PBLK : seg;
        const int nchunk = nseg & 3, nrow = nseg >> 2;
        const int ny = nrow % HC + CROP, nb = nrow / HC;
        int nx = CROP + nchunk * 256 + tid;
        nx = nx > 1018 ? 1018 : nx;
        const float* fb = flow + (size_t)nb * 2 * HW;
        const unsigned fo = (unsigned)(ny * WW + nx) * 4u;

        // ---- ONE asm block: 22 loads issued back-to-back. Early-clobber
        //      (=&v) guarantees outputs never alias address inputs (async
        //      writeback!). All results forced live -> ~20 misses in flight.
        f4 A00, A01, A02, A03, A10, A11, A12, A13;
        f4 A20, A21, A22, A23, A30, A31, A32, A33;
        float i0v, i1v, i2v, i3v;
        asm volatile(
            "global_load_dwordx4 %[a00], %[o0], %[t0]\n\t"
            "global_load_dwordx4 %[a01], %[o1], %[t0]\n\t"
            "global_load_dwordx4 %[a02], %[o2], %[t0]\n\t"
            "global_load_dwordx4 %[a03], %[o3], %[t0]\n\t"
            "global_load_dwordx4 %[a10], %[o0], %[t1]\n\t"
            "global_load_dwordx4 %[a11], %[o1], %[t1]\n\t"
            "global_load_dwordx4 %[a12], %[o2], %[t1]\n\t"
            "global_load_dwordx4 %[a13], %[o3], %[t1]\n\t"
            "global_load_dwordx4 %[a20], %[o0], %[t2]\n\t"
            "global_load_dwordx4 %[a21], %[o1], %[t2]\n\t"
            "global_load_dwordx4 %[a22], %[o2], %[t2]\n\t"
            "global_load_dwordx4 %[a23], %[o3], %[t2]\n\t"
            "global_load_dwordx4 %[a30], %[o0], %[t3]\n\t"
            "global_load_dwordx4 %[a31], %[o1], %[t3]\n\t"
            "global_load_dwordx4 %[a32], %[o2], %[t3]\n\t"
            "global_load_dwordx4 %[a33], %[o3], %[t3]\n\t"
            "global_load_dword %[i0], %[po], %[b0]\n\t"
            "global_load_dword %[i1], %[po], %[b1]\n\t"
            "global_load_dword %[i2], %[po], %[b2]\n\t"
            "global_load_dword %[i3], %[po], %[b3]\n\t"
            "global_load_dword %[nfx], %[fo], %[f0]\n\t"
            "global_load_dword %[nfy], %[fo], %[f1]"
            : [a00] "=&v"(A00), [a01] "=&v"(A01), [a02] "=&v"(A02),
              [a03] "=&v"(A03), [a10] "=&v"(A10), [a11] "=&v"(A11),
              [a12] "=&v"(A12), [a13] "=&v"(A13), [a20] "=&v"(A20),
              [a21] "=&v"(A21), [a22] "=&v"(A22), [a23] "=&v"(A23),
              [a30] "=&v"(A30), [a31] "=&v"(A31), [a32] "=&v"(A32),
              [a33] "=&v"(A33), [i0] "=&v"(i0v), [i1] "=&v"(i1v),
              [i2] "=&v"(i2v), [i3] "=&v"(i3v), [nfx] "=&v"(dxn),
              [nfy] "=&v"(dyn)
            : [o0] "v"(o0), [o1] "v"(o1), [o2] "v"(o2), [o3] "v"(o3),
              [po] "v"(po), [fo] "v"(fo),
              [t0] "s"(tgt_b), [t1] "s"(tgt_b + HW), [t2] "s"(tgt_b + 2 * HW),
              [t3] "s"(tgt_b + 3 * HW),
              [b0] "s"(in_b), [b1] "s"(in_b + HW), [b2] "s"(in_b + 2 * HW),
              [b3] "s"(in_b + 3 * HW),
              [f0] "s"(fb), [f1] "s"(fb + HW)
            : "memory");
        asm volatile("s_waitcnt vmcnt(0)" ::: "memory");
        __builtin_amdgcn_sched_barrier(0);
        // ---- all 22 results (incl. next flow) now valid ----

        if (valid) {
            if (fastc) {
                float v0 = wy0 * dot4(A00, wx0, wx1, wx2, wx3) +
                           wy1 * dot4(A01, wx0, wx1, wx2, wx3) +
                           wy2 * dot4(A02, wx0, wx1, wx2, wx3) +
                           wy3 * dot4(A03, wx0, wx1, wx2, wx3);
                float v1 = wy0 * dot4(A10, wx0, wx1, wx2, wx3) +
                           wy1 * dot4(A11, wx0, wx1, wx2, wx3) +
                           wy2 * dot4(A12, wx0, wx1, wx2, wx3) +
                           wy3 * dot4(A13, wx0, wx1, wx2, wx3);
                float v2 = wy0 * dot4(A20, wx0, wx1, wx2, wx3) +
                           wy1 * dot4(A21, wx0, wx1, wx2, wx3) +
                           wy2 * dot4(A22, wx0, wx1, wx2, wx3) +
                           wy3 * dot4(A23, wx0, wx1, wx2, wx3);
                float v3 = wy0 * dot4(A30, wx0, wx1, wx2, wx3) +
                           wy1 * dot4(A31, wx0, wx1, wx2, wx3) +
                           wy2 * dot4(A32, wx0, wx1, wx2, wx3) +
                           wy3 * dot4(A33, wx0, wx1, wx2, wx3);
                lsum += fabsf(i0v - v0) + fabsf(i1v - v1) + fabsf(i2v - v2) +
                        fabsf(i3v - v3);
            } else {
                lsum += px_slow(tgt_b, in_b, pix, bx, by, wx0, wx1, wx2, wx3,
                                wy0, wy1, wy2, wy3);
            }
        }
    }

    // wave-64 shuffle reduction + per-block partial (no global atomic)
#pragma unroll
    for (int off2 = 32; off2 > 0; off2 >>= 1) lsum += __shfl_down(lsum, off2);

    __shared__ float sm[4];
    if (lane == 0) sm[wv] = lsum;
    __syncthreads();
    if (tid == 0) wsbuf[blockIdx.x] = sm[0] + sm[1] + sm[2] + sm[3];
}

__global__ __launch_bounds__(1024) void reduce_k(const float* __restrict__ ws,
                                                 float* __restrict__ out) {
    float s = 0.0f;
    for (int i = threadIdx.x; i < PBLK; i += 1024) s += ws[i];
#pragma unroll
    for (int off = 32; off > 0; off >>= 1) s += __shfl_down(s, off);
    __shared__ float sm[16];
    const int lane = threadIdx.x & 63;
    const int wv = threadIdx.x >> 6;
    if (lane == 0) sm[wv] = s;
    __syncthreads();
    if (threadIdx.x == 0) {
        float t = 0.0f;
#pragma unroll
        for (int i = 0; i < 16; ++i) t += sm[i];
        constexpr float inv_count = 1.0f / ((float)BB * CC * HC * WC);
        out[0] = t * inv_count;
    }
}

extern "C" void kernel_launch(void* const* d_in, const int* in_sizes, int n_in,
                              void* d_out, int out_size, void* d_ws,
                              size_t ws_size, hipStream_t stream) {
    const float* input = (const float*)d_in[0];
    const float* target = (const float*)d_in[1];
    const float* flow = (const float*)d_in[2];
    float* ws = (float*)d_ws;
    float* out = (float*)d_out;

    warp_loss_k<<<PBLK, 256, 0, stream>>>(input, target, flow, ws);
    reduce_k<<<1, 1024, 0, stream>>>(ws, out);
}

// Round 13
// 130.180 us; speedup vs baseline: 14.2392x; 1.3223x over previous
//
#include <hip/hip_runtime.h>

// Problem constants (static from reference setup_inputs)
constexpr int BB = 8, CC = 4, HH = 1024, WW = 1024, CROP = 5;
constexpr int HC = HH - 2 * CROP, WC = WW - 2 * CROP;   // 1014 x 1014
constexpr int HW = HH * WW;
constexpr float AA = -0.75f;                            // PyTorch bicubic A

constexpr int NSTRIP = 16;                 // vertical strips (64 rows each)
constexpr int GRID = 32 * NSTRIP;          // (8 b x 4 chunks) x 16 = 512 blocks
constexpr int RING = 16;                   // row slots (slot = row & 15)
constexpr int SWID = 272;                  // floats per slot (256 + halo, 4-aligned)
constexpr int CH_STRIDE = RING * SWID;     // 4352 floats per channel

typedef __attribute__((address_space(1))) const void gv_t;
typedef __attribute__((address_space(3))) void lv_t;

// reflection valid for |i| <= 2046
__device__ __forceinline__ int reflect_small(int i) {
    int r = i < 0 ? -i : i;
    return r > (HH - 1) ? 2 * (HH - 1) - r : r;
}

__device__ __forceinline__ void cubic_w(float t, float& w0, float& w1,
                                        float& w2, float& w3) {
    float t1 = t + 1.0f;
    w0 = ((AA * t1 - 5.0f * AA) * t1 + 8.0f * AA) * t1 - 4.0f * AA;
    w1 = ((AA + 2.0f) * t - (AA + 3.0f)) * t * t + 1.0f;
    float s = 1.0f - t;
    w2 = ((AA + 2.0f) * s - (AA + 3.0f)) * s * s + 1.0f;
    float s2 = 2.0f - t;
    w3 = ((AA * s2 - 5.0f * AA) * s2 + 8.0f * AA) * s2 - 4.0f * AA;
}

// rare fallback (~1e-4 of pixels): scalar reflected global taps, all channels
__device__ __noinline__ float px_slow(const float* __restrict__ tgt_b,
                                      const float* __restrict__ in_b, int pix,
                                      int bx, int by, float wx0, float wx1,
                                      float wx2, float wx3, float wy0,
                                      float wy1, float wy2, float wy3) {
    const int r0 = reflect_small(by - 1) * WW;
    const int r1 = reflect_small(by) * WW;
    const int r2 = reflect_small(by + 1) * WW;
    const int r3 = reflect_small(by + 2) * WW;
    const int c0 = reflect_small(bx - 1);
    const int c1 = reflect_small(bx);
    const int c2 = reflect_small(bx + 1);
    const int c3 = reflect_small(bx + 2);
    float acc = 0.0f;
#pragma unroll
    for (int c = 0; c < CC; ++c) {
        const float* tb = tgt_b + c * HW;
        float q0 = wx0 * tb[r0 + c0] + wx1 * tb[r0 + c1] + wx2 * tb[r0 + c2] +
                   wx3 * tb[r0 + c3];
        float q1 = wx0 * tb[r1 + c0] + wx1 * tb[r1 + c1] + wx2 * tb[r1 + c2] +
                   wx3 * tb[r1 + c3];
        float q2 = wx0 * tb[r2 + c0] + wx1 * tb[r2 + c1] + wx2 * tb[r2 + c2] +
                   wx3 * tb[r2 + c3];
        float q3 = wx0 * tb[r3 + c0] + wx1 * tb[r3 + c1] + wx2 * tb[r3 + c2] +
                   wx3 * tb[r3 + c3];
        float v = wy0 * q0 + wy1 * q1 + wy2 * q2 + wy3 * q3;
        acc += fabsf(in_b[c * HW + pix] - v);
    }
    return acc;
}

__global__ __launch_bounds__(256, 2) void warp_loss_k(
    const float* __restrict__ input, const float* __restrict__ target,
    const float* __restrict__ flow, float* __restrict__ wsbuf) {
    __shared__ float cache[CC * CH_STRIDE];   // 4 ch x 16 slots x 272 = 69.6 KB
    const int tid = (int)threadIdx.x;
    const int wv = tid >> 6, lane = tid & 63;

    const int colid = (int)blockIdx.x & 31;   // (b, chunk)
    const int strip = (int)blockIdx.x >> 5;
    const int b = colid >> 2;
    const int chunk = colid & 3;
    const int x0 = CROP + chunk * 256;
    // window start col: 4-aligned, clamped so [wscol, wscol+271] is in-image
    const int wscol = chunk == 0 ? 0 : chunk == 1 ? 252 : chunk == 2 ? 508 : 752;
    const int y0 = CROP + strip * 64;
    const int y1 = min(y0 + 64, CROP + HC);   // exclusive

    const int x = x0 + tid;
    const bool valid_px = x <= 1018;
    const int xc = valid_px ? x : 1018;

    const float* tgt_b = target + (size_t)b * CC * HW;
    const float* in_b = input + (size_t)b * CC * HW;
    const float* flow_b = flow + (size_t)b * 2 * HW;

    // wave wv stages channel wv; 2 global_load_lds per row:
    //   floats [0,255] via 16B/lane, floats [208,271] via 4B/lane (overlap ok,
    //   identical source bytes)
    const float* plane = tgt_b + (size_t)wv * HW;
    const int chbase = wv * CH_STRIDE;

    // prologue: rows y0-5 .. y0+5 (always within [0,1023] -> no reflection)
#pragma unroll 1
    for (int k = 0; k < 11; ++k) {
        const int r = y0 - 5 + k;
        const int slot = r & (RING - 1);
        const float* src = plane + (size_t)r * WW + wscol;
        __builtin_amdgcn_global_load_lds((gv_t*)(src + lane * 4),
                                         (lv_t*)&cache[chbase + slot * SWID],
                                         16, 0, 0);
        __builtin_amdgcn_global_load_lds(
            (gv_t*)(src + 208 + lane),
            (lv_t*)&cache[chbase + slot * SWID + 208], 4, 0, 0);
    }
    __syncthreads();

    float lsum = 0.0f;

    for (int y = y0; y < y1; ++y) {
        // stage row y+6 (slot holds old row y-10, disjoint from read window
        // y-5..y+5). Skip past image bottom (last strip: r would hit 1024).
        {
            const int r = y + 6;
            if (r < HH) {   // wave-uniform
                const int slot = r & (RING - 1);
                const float* src = plane + (size_t)r * WW + wscol;
                __builtin_amdgcn_global_load_lds(
                    (gv_t*)(src + lane * 4),
                    (lv_t*)&cache[chbase + slot * SWID], 16, 0, 0);
                __builtin_amdgcn_global_load_lds(
                    (gv_t*)(src + 208 + lane),
                    (lv_t*)&cache[chbase + slot * SWID + 208], 4, 0, 0);
            }
        }

        const int pix = y * WW + xc;
        const float dx = flow_b[pix];
        const float dy = flow_b[HW + pix];
        const float i0v = in_b[pix];
        const float i1v = in_b[HW + pix];
        const float i2v = in_b[2 * HW + pix];
        const float i3v = in_b[3 * HW + pix];

        const float fx = (float)xc + dx;
        const float fy = (float)y + dy;
        const float bxf = floorf(fx), byf = floorf(fy);
        const int bx = (int)bxf, by = (int)byf;
        const float tx = fx - bxf, ty = fy - byf;

        float wx0, wx1, wx2, wx3, wy0, wy1, wy2, wy3;
        cubic_w(tx, wx0, wx1, wx2, wx3);
        cubic_w(ty, wy0, wy1, wy2, wy3);

        const int d = by - y;
        const int cx = bx - 1 - wscol;
        const bool fast =
            valid_px & (d >= -4) & (d <= 3) & (cx >= 0) & (cx <= 268);

        if (fast) {
            const int t = (by - 1) & (RING - 1);
            float v0 = 0.0f, v1 = 0.0f, v2 = 0.0f, v3 = 0.0f;
#pragma unroll
            for (int j = 0; j < 4; ++j) {
                const int s = (t + j) & (RING - 1);
                const int base = s * SWID + cx;
                const float wyj =
                    j == 0 ? wy0 : j == 1 ? wy1 : j == 2 ? wy2 : wy3;
                const float* p0 = &cache[base];
                const float* p1 = &cache[CH_STRIDE + base];
                const float* p2 = &cache[2 * CH_STRIDE + base];
                const float* p3 = &cache[3 * CH_STRIDE + base];
                v0 += wyj * (p0[0] * wx0 + p0[1] * wx1 + p0[2] * wx2 + p0[3] * wx3);
                v1 += wyj * (p1[0] * wx0 + p1[1] * wx1 + p1[2] * wx2 + p1[3] * wx3);
                v2 += wyj * (p2[0] * wx0 + p2[1] * wx1 + p2[2] * wx2 + p2[3] * wx3);
                v3 += wyj * (p3[0] * wx0 + p3[1] * wx1 + p3[2] * wx2 + p3[3] * wx3);
            }
            lsum += fabsf(i0v - v0) + fabsf(i1v - v1) + fabsf(i2v - v2) +
                    fabsf(i3v - v3);
        } else if (valid_px) {
            lsum += px_slow(tgt_b, in_b, pix, bx, by, wx0, wx1, wx2, wx3,
                            wy0, wy1, wy2, wy3);
        }

        // stage(y+6) landed + all reads of this window done before slot reuse
        __syncthreads();
    }

    // wave-64 shuffle reduction + per-block partial (no global atomic)
#pragma unroll
    for (int off2 = 32; off2 > 0; off2 >>= 1) lsum += __shfl_down(lsum, off2);

    __shared__ float sm[4];
    if (lane == 0) sm[wv] = lsum;
    __syncthreads();
    if (tid == 0) wsbuf[blockIdx.x] = sm[0] + sm[1] + sm[2] + sm[3];
}

__global__ __launch_bounds__(1024) void reduce_k(const float* __restrict__ ws,
                                                 float* __restrict__ out) {
    float s = 0.0f;
    for (int i = threadIdx.x; i < GRID; i += 1024) s += ws[i];
#pragma unroll
    for (int off = 32; off > 0; off >>= 1) s += __shfl_down(s, off);
    __shared__ float sm[16];
    const int lane = threadIdx.x & 63;
    const int wv = threadIdx.x >> 6;
    if (lane == 0) sm[wv] = s;
    __syncthreads();
    if (threadIdx.x == 0) {
        float t = 0.0f;
#pragma unroll
        for (int i = 0; i < 16; ++i) t += sm[i];
        constexpr float inv_count = 1.0f / ((float)BB * CC * HC * WC);
        out[0] = t * inv_count;
    }
}

extern "C" void kernel_launch(void* const* d_in, const int* in_sizes, int n_in,
                              void* d_out, int out_size, void* d_ws,
                              size_t ws_size, hipStream_t stream) {
    const float* input = (const float*)d_in[0];
    const float* target = (const float*)d_in[1];
    const float* flow = (const float*)d_in[2];
    float* ws = (float*)d_ws;
    float* out = (float*)d_out;

    warp_loss_k<<<GRID, 256, 0, stream>>>(input, target, flow, ws);
    reduce_k<<<1, 1024, 0, stream>>>(ws, out);
}